// Round 4
// baseline (148.396 us; speedup 1.0000x reference)
//
#include <hip/hip_runtime.h>
#include <hip/hip_bf16.h>

#define DEVINL __device__ __forceinline__

typedef float  f32x4_t  __attribute__((ext_vector_type(4)));
typedef float  f32x16_t __attribute__((ext_vector_type(16)));
typedef short  bf16x8_t __attribute__((ext_vector_type(8)));

#define MFMA16(a,b,c) __builtin_amdgcn_mfma_f32_16x16x32_bf16((a),(b),(c),0,0,0)
#define MFMA32(a,b,c) __builtin_amdgcn_mfma_f32_32x32x16_bf16((a),(b),(c),0,0,0)

DEVINL unsigned short f2bf(float f) {
  union { float f; unsigned u; } v; v.f = f;
  unsigned r = v.u + 0x7fffu + ((v.u >> 16) & 1u);   // round-to-nearest-even
  return (unsigned short)(r >> 16);
}

DEVINL unsigned pk2bf(float lo, float hi) {          // bf16(lo) | bf16(hi)<<16, RNE
  union { __hip_bfloat162 h2; unsigned u; } v;
  v.h2 = __float22bfloat162_rn(make_float2(lo, hi));
  return v.u;
}

// ============================ fragment-order layouts ============================
// I/J (bf16): idx = (rowtile*8 + mc)*512 + r32*16 + h*8 + e
//   rowtile = position index (I: i, J: j), r32 = channel x/y (0..31),
//   m = mc*16 + h*8 + e.  A/B frag for 32x32x16 = 16B at (r32=lane&31, h=lane>>5).
// W (bf16): idx = (oT*64 + kc)*512 + o32*16 + h*8 + e; o = oT*32+o32.
//   K-position kpos = kc*16 + h*8 + e carries f-element with kpos = y*32 + x
//   (f = x*32 + y in the reference) — matches fl's kpos order in kB.

// ---------------- kernel A: LayerNorm + proj + split (+ final_w conversion) ------
// 256 blocks x 512 thr, exactly 1 block/CU (119.8 KB dynamic LDS), one l each,
// all 128 m rows. proj_w loaded+converted ONCE per block (was 4x). final_w
// conversion folded into the x-load latency shadow (tid<128, 1 ushort4 each) --
// no separate conversion blocks. LDS row stride 268 (row offset = 6 mod 32
// words) -> near-conflict-free ds_read_b128 in the proj GEMM.
__global__ __launch_bounds__(512) void kA(const float* __restrict__ x,
                                          const float* __restrict__ nw,
                                          const float* __restrict__ nb,
                                          const float* __restrict__ pw,
                                          const float* __restrict__ pb,
                                          const float* __restrict__ fw,
                                          unsigned short* __restrict__ Wb,
                                          unsigned short* __restrict__ Ig,
                                          unsigned short* __restrict__ Jg) {
  extern __shared__ unsigned short sA[];
  unsigned short* xnl = sA;                     // 128 rows x 268
  unsigned short* pwl = sA + 128 * 268;         // 64 d x 268
  unsigned short* ep  = sA + (128 + 64) * 268;  // 64 d x 132 (m-local transpose)
  const int tid  = threadIdx.x;
  const int wv   = tid >> 6;                    // wave 0..7
  const int lane = tid & 63;
  const int q    = lane >> 4;
  const int ln16 = lane & 15;
  const int l    = blockIdx.x;                  // 0..255

  // ---- issue x loads (16 rows per wave: row = i*8 + wv) ----
  const float4* xs = (const float4*)x;
  float4 v[16];
#pragma unroll
  for (int i = 0; i < 16; i++)
    v[i] = xs[(size_t)(i * 8 + wv) * 16384 + l * 64 + lane];
  float4 nw4 = ((const float4*)nw)[lane];
  float4 nb4 = ((const float4*)nb)[lane];

  // ---- final_w fp32 -> bf16 (kpos = y*32+x), hidden under x-load latency ----
  if (tid < 128) {
    int T = blockIdx.x * 128 + tid;             // 0..32767
    int o     = T >> 8;
    int kpos0 = (T & 255) * 4;                  // 4 consecutive kpos (same y)
    int y  = kpos0 >> 5;
    int x0 = kpos0 & 31;
    const float* fo = fw + o * 1024 + y;
    ushort4 u;
    u.x = f2bf(fo[(x0 + 0) * 32]);
    u.y = f2bf(fo[(x0 + 1) * 32]);
    u.z = f2bf(fo[(x0 + 2) * 32]);
    u.w = f2bf(fo[(x0 + 3) * 32]);
    size_t off = (size_t)((o >> 5) * 64 + (kpos0 >> 4)) * 512 + (o & 31) * 16
               + ((kpos0 >> 3) & 1) * 8 + (kpos0 & 7);
    *(ushort4*)&Wb[off] = u;
  }

  // ---- proj_w -> pwl (once per block; 4096 float4 over 512 thr) ----
  const float4* ps = (const float4*)pw;
#pragma unroll
  for (int i = 0; i < 8; i++) {
    int idx  = i * 512 + tid;
    int row  = idx >> 6;
    int col4 = idx & 63;
    float4 w4 = ps[idx];
    ushort4 u;
    u.x = f2bf(w4.x); u.y = f2bf(w4.y); u.z = f2bf(w4.z); u.w = f2bf(w4.w);
    *(ushort4*)&pwl[row * 268 + col4 * 4] = u;
  }

  // ---- LayerNorm per row -> xnl ----
#pragma unroll
  for (int i = 0; i < 16; i++) {
    float s  = v[i].x + v[i].y + v[i].z + v[i].w;
    float ss = v[i].x * v[i].x + v[i].y * v[i].y + v[i].z * v[i].z + v[i].w * v[i].w;
#pragma unroll
    for (int off = 32; off > 0; off >>= 1) {
      s  += __shfl_xor(s, off);
      ss += __shfl_xor(ss, off);
    }
    float mu  = s * (1.0f / 256.0f);
    float var = ss * (1.0f / 256.0f) - mu * mu;
    float rs  = rsqrtf(var + 1e-5f);
    ushort4 u;
    u.x = f2bf((v[i].x - mu) * rs * nw4.x + nb4.x);
    u.y = f2bf((v[i].y - mu) * rs * nw4.y + nb4.y);
    u.z = f2bf((v[i].z - mu) * rs * nw4.z + nb4.z);
    u.w = f2bf((v[i].w - mu) * rs * nw4.w + nb4.w);
    *(ushort4*)&xnl[(i * 8 + wv) * 268 + lane * 4] = u;
  }
  __syncthreads();

  // ---- proj GEMM: wave wv -> m-tile (16 rows), all 64 d ----
  f32x4_t acc[4] = {{0,0,0,0},{0,0,0,0},{0,0,0,0},{0,0,0,0}};
#pragma unroll
  for (int kc = 0; kc < 8; kc++) {
    bf16x8_t a = *(const bf16x8_t*)&xnl[(wv * 16 + ln16) * 268 + kc * 32 + q * 8];
#pragma unroll
    for (int dt = 0; dt < 4; dt++) {
      bf16x8_t b = *(const bf16x8_t*)&pwl[(dt * 16 + ln16) * 268 + kc * 32 + q * 8];
      acc[dt] = MFMA16(a, b, acc[dt]);
    }
  }
#pragma unroll
  for (int dt = 0; dt < 4; dt++) {
    int d = dt * 16 + ln16;
    float bias  = pb[d];
    float scale = (d & 1) ? 1.0f : (1.0f / 128.0f);   // fold 1/m into I side
#pragma unroll
    for (int r = 0; r < 4; r++)
      ep[d * 132 + wv * 16 + q * 4 + r] = f2bf((acc[dt][r] + bias) * scale);
  }
  __syncthreads();

  // ---- frag-order stores: I from even d (channel = hh), J from odd d ----
  const int hh  = tid >> 4;                    // 0..31 (x or y)
  const int mg0 = tid & 15;
#pragma unroll
  for (int g2 = 0; g2 < 2; g2++) {
    int mg = g2 * 16 + mg0;                    // m-quad 0..31 (m = 4*mg)
    size_t off = (size_t)(l * 8 + (mg >> 2)) * 512 + hh * 16
               + ((mg >> 1) & 1) * 8 + (mg & 1) * 4;
    ushort4 vi = *(const ushort4*)&ep[(2 * hh) * 132 + mg * 4];
    *(ushort4*)&Ig[off] = vi;
    ushort4 vj = *(const ushort4*)&ep[(2 * hh + 1) * 132 + mg * 4];
    *(ushort4*)&Jg[off] = vj;
  }
}

// ---------------- kernel B: fused outer-product-mean + final GEMM ----------------
// REVERT to round-1 config (best measured: 50.36 us). 2048 blocks x 256 thr;
// block = (p: 2 i_l) x (t: 16 j_l) -> 32 output rows. fl[32][1048] bf16 (67 KB)
// -> 2 resident blocks/CU: independent barrier domains overlap. GEMM1: wave w ->
// jl {4w..4w+3}, both il; I frags in regs. GEMM2: wave = ot, FULL K=1024, no
// K-split reduction, 1 barrier total. W ring depth-8, A ring depth-4.
__global__ __launch_bounds__(256, 2) void kB(const unsigned short* __restrict__ Ig,
                                             const unsigned short* __restrict__ Jg,
                                             const unsigned short* __restrict__ Wb,
                                             const float* __restrict__ fb,
                                             float* __restrict__ out) {
  extern __shared__ unsigned short fl[];     // 32 x 1048
  constexpr int P = 1048;
  const int tid  = threadIdx.x;
  const int w    = tid >> 6;                 // wave 0..3
  const int lane = tid & 63;
  const int ln32 = lane & 31;
  const int h    = lane >> 5;
  const int p    = blockIdx.x >> 4;          // i_l pair 0..127
  const int t    = blockIdx.x & 15;          // j_l tile-of-16 0..15

  // ---------- GEMM1: wave w -> jl in {4w..4w+3}; both il ----------
  bf16x8_t af[2][8];
#pragma unroll
  for (int u = 0; u < 2; u++)
#pragma unroll
    for (int mc = 0; mc < 8; mc++)
      af[u][mc] = *(const bf16x8_t*)&Ig[(size_t)((p * 2 + u) * 8 + mc) * 512 + ln32 * 16 + h * 8];

#pragma unroll
  for (int s = 0; s < 4; s++) {
    const int jl = 4 * w + s;
    const size_t jbase = (size_t)(t * 16 + jl) * 4096 + ln32 * 16 + h * 8;
    bf16x8_t jb[8];
#pragma unroll
    for (int mc = 0; mc < 8; mc++) jb[mc] = *(const bf16x8_t*)&Jg[jbase + mc * 512];
    f32x16_t c[2];
#pragma unroll
    for (int i = 0; i < 16; i++) { c[0][i] = 0.f; c[1][i] = 0.f; }
#pragma unroll
    for (int mc = 0; mc < 8; mc++) {
      c[0] = MFMA32(af[0][mc], jb[mc], c[0]);
      c[1] = MFMA32(af[1][mc], jb[mc], c[1]);
    }
    // lane: col y = ln32; reg quad g covers x = 8g + 4h .. +3 -> one b64 each
#pragma unroll
    for (int u = 0; u < 2; u++) {
      unsigned short* fr = &fl[(u * 16 + jl) * P];
#pragma unroll
      for (int g = 0; g < 4; g++) {
        int cp = (4 * ln32 + g) ^ (ln32 & 7);
        uint2 pv;
        pv.x = pk2bf(c[u][4 * g + 0], c[u][4 * g + 1]);
        pv.y = pk2bf(c[u][4 * g + 2], c[u][4 * g + 3]);
        *(uint2*)&fr[cp * 8 + h * 4] = pv;
      }
    }
  }

  // ---------- GEMM2: wave = ot (32 o-cols), full K = 1024 ----------
  const int ot = w;
  const unsigned short* Wp = Wb + (size_t)(ot * 64) * 512 + ln32 * 16 + h * 8;
  bf16x8_t bq[8];
  bq[0] = *(const bf16x8_t*)&Wp[0];          // pre-barrier W prefetch
  bq[1] = *(const bf16x8_t*)&Wp[512];

  __syncthreads();                           // fl ready (the only barrier)

#pragma unroll
  for (int i = 2; i < 8; i++) bq[i] = *(const bf16x8_t*)&Wp[(size_t)i * 512];

  // A-frag: row = ln32; chunk c = kc*2 + h, swizzled
#define LDA(kc) (*(const bf16x8_t*)&fl[ln32 * P + \
    (((((kc) * 2 + h)) ^ (((kc) >> 1) & 7)) * 8)])

  f32x16_t o2[2];                            // even/odd-kc partial sums
#pragma unroll
  for (int i = 0; i < 16; i++) { o2[0][i] = 0.f; o2[1][i] = 0.f; }

  bf16x8_t aq[4];
  aq[0] = LDA(0); aq[1] = LDA(1); aq[2] = LDA(2); aq[3] = LDA(3);

#pragma unroll
  for (int kc = 0; kc < 64; kc += 2) {
    bf16x8_t ac0 = aq[kc & 3],      ac1 = aq[(kc + 1) & 3];
    bf16x8_t bc0 = bq[kc & 7],      bc1 = bq[(kc + 1) & 7];
    if (kc < 60) { aq[kc & 3] = LDA(kc + 4); aq[(kc + 1) & 3] = LDA(kc + 5); }
    if (kc < 56) {
      bq[kc & 7]       = *(const bf16x8_t*)&Wp[(size_t)(kc + 8) * 512];
      bq[(kc + 1) & 7] = *(const bf16x8_t*)&Wp[(size_t)(kc + 9) * 512];
    }
    o2[0] = MFMA32(ac0, bc0, o2[0]);
    o2[1] = MFMA32(ac1, bc1, o2[1]);
  }
#undef LDA

  // ---------- epilogue: all waves store, no reduction ----------
  const float bias = fb[ot * 32 + ln32];
  float* ob = out + ((size_t)(p * 2) * 256 + t * 16) * 128 + ot * 32 + ln32;
#pragma unroll
  for (int r = 0; r < 16; r++) {
    int br = (r & 3) + 8 * (r >> 2) + 4 * h;         // local row 0..31
    ob[(br >> 4) * 32768 + (br & 15) * 128] = o2[0][r] + o2[1][r] + bias;
  }
}

extern "C" void kernel_launch(void* const* d_in, const int* in_sizes, int n_in,
                              void* d_out, int out_size, void* d_ws, size_t ws_size,
                              hipStream_t stream) {
  const float* x1d     = (const float*)d_in[0];
  const float* norm_w  = (const float*)d_in[1];
  const float* norm_b  = (const float*)d_in[2];
  const float* proj_w  = (const float*)d_in[3];
  const float* proj_b  = (const float*)d_in[4];
  const float* final_w = (const float*)d_in[5];
  const float* final_b = (const float*)d_in[6];
  float* outp          = (float*)d_out;

  // workspace carve (bf16): W (128*1024), I (256*32*128), J (256*32*128)
  unsigned short* Wb  = (unsigned short*)d_ws;
  unsigned short* Igp = Wb + 131072;
  unsigned short* Jgp = Igp + 1048576;

  const int ka_lds = (128 * 268 + 64 * 268 + 64 * 132) * 2;  // 119808 B -> 1 block/CU
  const int kb_lds = 32 * 1048 * 2;                          // 67072 B  -> 2 blocks/CU
  hipFuncSetAttribute((const void*)kA, hipFuncAttributeMaxDynamicSharedMemorySize, ka_lds);
  hipFuncSetAttribute((const void*)kB, hipFuncAttributeMaxDynamicSharedMemorySize, kb_lds);

  kA<<<256, 512, ka_lds, stream>>>(x1d, norm_w, norm_b, proj_w, proj_b, final_w, Wb, Igp, Jgp);
  kB<<<2048, 256, kb_lds, stream>>>(Igp, Jgp, Wb, final_b, outp);
}